// Round 1
// baseline (560.239 us; speedup 1.0000x reference)
//
#include <hip/hip_runtime.h>

#define KNN_INF 3.0e38f

// ---------------- kNN kernel: one thread per dense point ----------------
__global__ void knn_kernel(const float* __restrict__ p1, // [B,N1,3]
                           const float* __restrict__ p2, // [B,N2,3]
                           int*   __restrict__ idx,      // [B,N1,3]
                           float* __restrict__ w,        // [B,N1,3]
                           int N1, int N2) {
    extern __shared__ float sm[]; // N2 * 4 : x,y,z,|p|^2
    int b = blockIdx.y;
    const float* p2b = p2 + (size_t)b * N2 * 3;
    for (int m = threadIdx.x; m < N2; m += blockDim.x) {
        float x = p2b[m * 3 + 0], y = p2b[m * 3 + 1], z = p2b[m * 3 + 2];
        sm[m * 4 + 0] = x; sm[m * 4 + 1] = y; sm[m * 4 + 2] = z;
        sm[m * 4 + 3] = x * x + y * y + z * z;
    }
    __syncthreads();
    int n = blockIdx.x * blockDim.x + threadIdx.x;
    if (n >= N1) return;
    const float* p1b = p1 + ((size_t)b * N1 + n) * 3;
    float px = p1b[0], py = p1b[1], pz = p1b[2];
    float s1 = px * px + py * py + pz * pz;
    float d0 = KNN_INF, d1 = KNN_INF, d2 = KNN_INF;
    int i0 = 0, i1 = 0, i2 = 0;
    for (int m = 0; m < N2; ++m) {
        float dot = px * sm[m * 4 + 0] + py * sm[m * 4 + 1] + pz * sm[m * 4 + 2];
        float d = s1 - 2.0f * dot + sm[m * 4 + 3];
        if (d < d2) {
            if (d < d1) {
                d2 = d1; i2 = i1;
                if (d < d0) { d1 = d0; i1 = i0; d0 = d; i0 = m; }
                else        { d1 = d;  i1 = m; }
            } else { d2 = d; i2 = m; }
        }
    }
    float dd0 = fmaxf(d0, 0.0f), dd1 = fmaxf(d1, 0.0f), dd2 = fmaxf(d2, 0.0f);
    float w0 = 1.0f / (dd0 + 1e-8f);
    float w1 = 1.0f / (dd1 + 1e-8f);
    float w2 = 1.0f / (dd2 + 1e-8f);
    float wsum = w0 + w1 + w2;
    w0 /= wsum; w1 /= wsum; w2 /= wsum;
    size_t base = ((size_t)b * N1 + n) * 3;
    idx[base + 0] = i0; idx[base + 1] = i1; idx[base + 2] = i2;
    w[base + 0] = w0; w[base + 1] = w1; w[base + 2] = w2;
}

// -------- gather + concat: out[b,c,n] = c<C1 ? f1[b,c,n] : interp --------
__global__ void concat_interp_kernel(const float* __restrict__ f1, // [B,C1,N1]
                                     const float* __restrict__ x2, // [B,C2,N2]
                                     const int*   __restrict__ idx,
                                     const float* __restrict__ w,
                                     float* __restrict__ out,      // [B,C1+C2,N1]
                                     int C1, int C2, int N1, int N2) {
    int n = blockIdx.x * blockDim.x + threadIdx.x;
    int c = blockIdx.y;
    int b = blockIdx.z;
    if (n >= N1) return;
    int C = C1 + C2;
    float v;
    if (c < C1) {
        v = f1[((size_t)b * C1 + c) * N1 + n];
    } else {
        int c2 = c - C1;
        size_t base = ((size_t)b * N1 + n) * 3;
        const float* x2b = x2 + ((size_t)b * C2 + c2) * N2;
        v = x2b[idx[base + 0]] * w[base + 0]
          + x2b[idx[base + 1]] * w[base + 1]
          + x2b[idx[base + 2]] * w[base + 2];
    }
    out[((size_t)b * C + c) * N1 + n] = v;
}

// ------------- tiled GEMM + BN + ReLU: Y[b,o,n] = relu(g[o]*(W X) + b[o]) -------------
#define TO 32
#define TN 64
#define BK 16
__global__ __launch_bounds__(256) void conv_bn_relu_kernel(
    const float* __restrict__ X,  // [B,Cin,N]
    const float* __restrict__ W,  // [Cout,Cin]
    const float* __restrict__ g,
    const float* __restrict__ bv,
    float* __restrict__ Y,        // [B,Cout,N]
    int Cin, int Cout, int N) {
    __shared__ float Ws[BK][TO];
    __shared__ float Xs[BK][TN];
    int b = blockIdx.z;
    int oBase = blockIdx.y * TO;
    int nBase = blockIdx.x * TN;
    int tid = threadIdx.x;
    int tx = tid & 15;   // n
    int ty = tid >> 4;   // o
    float acc[2][4] = {{0.f, 0.f, 0.f, 0.f}, {0.f, 0.f, 0.f, 0.f}};
    const float* Xb = X + (size_t)b * Cin * N;
    for (int k0 = 0; k0 < Cin; k0 += BK) {
        for (int t = tid; t < TO * BK; t += 256) {
            int o = t / BK, kk = t % BK;
            Ws[kk][o] = W[(size_t)(oBase + o) * Cin + k0 + kk];
        }
        for (int t = tid; t < BK * TN; t += 256) {
            int kk = t / TN, nn = t % TN;
            Xs[kk][nn] = Xb[(size_t)(k0 + kk) * N + nBase + nn];
        }
        __syncthreads();
#pragma unroll
        for (int kk = 0; kk < BK; ++kk) {
            float w0 = Ws[kk][ty * 2 + 0];
            float w1 = Ws[kk][ty * 2 + 1];
            float4 xv = *reinterpret_cast<const float4*>(&Xs[kk][tx * 4]);
            acc[0][0] = fmaf(w0, xv.x, acc[0][0]);
            acc[0][1] = fmaf(w0, xv.y, acc[0][1]);
            acc[0][2] = fmaf(w0, xv.z, acc[0][2]);
            acc[0][3] = fmaf(w0, xv.w, acc[0][3]);
            acc[1][0] = fmaf(w1, xv.x, acc[1][0]);
            acc[1][1] = fmaf(w1, xv.y, acc[1][1]);
            acc[1][2] = fmaf(w1, xv.z, acc[1][2]);
            acc[1][3] = fmaf(w1, xv.w, acc[1][3]);
        }
        __syncthreads();
    }
#pragma unroll
    for (int r = 0; r < 2; ++r) {
        int o = oBase + ty * 2 + r;
        float gg = g[o], bb = bv[o];
        float4 st;
        st.x = fmaxf(fmaf(acc[r][0], gg, bb), 0.0f);
        st.y = fmaxf(fmaf(acc[r][1], gg, bb), 0.0f);
        st.z = fmaxf(fmaf(acc[r][2], gg, bb), 0.0f);
        st.w = fmaxf(fmaf(acc[r][3], gg, bb), 0.0f);
        *reinterpret_cast<float4*>(&Y[((size_t)b * Cout + o) * N + nBase + tx * 4]) = st;
    }
}

extern "C" void kernel_launch(void* const* d_in, const int* in_sizes, int n_in,
                              void* d_out, int out_size, void* d_ws, size_t ws_size,
                              hipStream_t stream) {
    const int B = 8;
    const int Ns[5]  = {8192, 2048, 512, 128, 32};
    const int CHs[5] = {32, 64, 128, 256, 512};

    const float* p[5];
    const float* f[5];
    for (int i = 0; i < 5; ++i) {
        p[i] = (const float*)d_in[2 * i];
        f[i] = (const float*)d_in[2 * i + 1];
    }

    float* ws = (float*)d_ws;
    int*   knn_idx = (int*)ws;                       // 8*8192*3 = 196608
    float* knn_w   = ws + 196608;                    // 196608
    float* concat  = ws + 2 * 196608;                // up to 8*96*8192 = 6291456
    float* bufA    = concat + 6291456;               // up to 8*32*8192 = 2097152
    float* out0    = bufA + 2097152;                 // 8*256*128 = 262144
    float* out1    = out0 + 262144;                  // 8*128*512 = 524288
    float* out2    = out1 + 524288;                  // 8*64*2048 = 1048576
    float* outs[4] = {out0, out1, out2, (float*)d_out};

    for (int s = 0; s < 4; ++s) {
        int lvl = 3 - s;
        int N1 = Ns[lvl], N2 = Ns[lvl + 1];
        int C1 = CHs[lvl];
        int C2 = (s == 0) ? CHs[4] : CHs[lvl + 1];
        int Cin = C1 + C2;
        int Cout = C1;
        const float* x2 = (s == 0) ? f[4] : outs[s - 1];
        const float* wa = (const float*)d_in[10 + s * 6 + 0];
        const float* ga = (const float*)d_in[10 + s * 6 + 1];
        const float* ba = (const float*)d_in[10 + s * 6 + 2];
        const float* wb = (const float*)d_in[10 + s * 6 + 3];
        const float* gb = (const float*)d_in[10 + s * 6 + 4];
        const float* bb = (const float*)d_in[10 + s * 6 + 5];

        // kNN
        dim3 kg((N1 + 255) / 256, B);
        size_t lds = (size_t)N2 * 4 * sizeof(float);
        knn_kernel<<<kg, 256, lds, stream>>>(p[lvl], p[lvl + 1], knn_idx, knn_w, N1, N2);

        // gather + concat
        dim3 cg((N1 + 255) / 256, Cin, B);
        concat_interp_kernel<<<cg, 256, 0, stream>>>(f[lvl], x2, knn_idx, knn_w,
                                                     concat, C1, C2, N1, N2);

        // conv_a
        dim3 ag(N1 / TN, Cout / TO, B);
        conv_bn_relu_kernel<<<ag, 256, 0, stream>>>(concat, wa, ga, ba, bufA, Cin, Cout, N1);

        // conv_b
        conv_bn_relu_kernel<<<ag, 256, 0, stream>>>(bufA, wb, gb, bb, outs[s], Cout, Cout, N1);
    }
}

// Round 2
// 394.854 us; speedup vs baseline: 1.4189x; 1.4189x over previous
//
#include <hip/hip_runtime.h>

#define KNN_INF 3.0e38f

// ---- kNN over a chunk of the sparse set: partial top-3 per (dense point, chunk) ----
__global__ void knn_chunk_kernel(const float* __restrict__ p1, // [B,N1,3]
                                 const float* __restrict__ p2, // [B,N2,3]
                                 float* __restrict__ pd,       // [B,N1,nchunk,3]
                                 int*   __restrict__ pi,       // [B,N1,nchunk,3]
                                 int N1, int N2, int chunk, int nchunk) {
    extern __shared__ float4 sm4[]; // chunk entries: x,y,z,|p|^2
    int z = blockIdx.z;
    int b = blockIdx.y;
    int m0 = z * chunk;
    const float* p2b = p2 + ((size_t)b * N2 + m0) * 3;
    for (int m = threadIdx.x; m < chunk; m += blockDim.x) {
        float x = p2b[m * 3 + 0], y = p2b[m * 3 + 1], zz = p2b[m * 3 + 2];
        sm4[m] = make_float4(x, y, zz, x * x + y * y + zz * zz);
    }
    __syncthreads();
    int n = blockIdx.x * blockDim.x + threadIdx.x;
    if (n >= N1) return;
    const float* p1b = p1 + ((size_t)b * N1 + n) * 3;
    float px = p1b[0], py = p1b[1], pz = p1b[2];
    float s1 = px * px + py * py + pz * pz;
    float d0 = KNN_INF, d1 = KNN_INF, d2 = KNN_INF;
    int i0 = 0, i1 = 0, i2 = 0;
    for (int m = 0; m < chunk; ++m) {
        float4 q = sm4[m];
        float dot = px * q.x + py * q.y + pz * q.z;
        float d = fmaf(-2.0f, dot, s1 + q.w);
        if (d < d2) {
            if (d < d1) {
                d2 = d1; i2 = i1;
                if (d < d0) { d1 = d0; i1 = i0; d0 = d; i0 = m; }
                else        { d1 = d;  i1 = m; }
            } else { d2 = d; i2 = m; }
        }
    }
    size_t base = (((size_t)b * N1 + n) * nchunk + z) * 3;
    pd[base + 0] = d0; pd[base + 1] = d1; pd[base + 2] = d2;
    pi[base + 0] = m0 + i0; pi[base + 1] = m0 + i1; pi[base + 2] = m0 + i2;
}

// ---- merge partial top-3s (in global-index order) + compute weights ----
__global__ void knn_merge_kernel(const float* __restrict__ pd,
                                 const int*   __restrict__ pi,
                                 int*   __restrict__ idx,  // [B*N1,3]
                                 float* __restrict__ w,    // [B*N1,3]
                                 int total, int nchunk) {
    int t = blockIdx.x * blockDim.x + threadIdx.x;
    if (t >= total) return;
    float d0 = KNN_INF, d1 = KNN_INF, d2 = KNN_INF;
    int i0 = 0, i1 = 0, i2 = 0;
    size_t base = (size_t)t * nchunk * 3;
    for (int c = 0; c < nchunk * 3; ++c) {
        float d = pd[base + c];
        int   i = pi[base + c];
        if (d < d2) {
            if (d < d1) {
                d2 = d1; i2 = i1;
                if (d < d0) { d1 = d0; i1 = i0; d0 = d; i0 = i; }
                else        { d1 = d;  i1 = i; }
            } else { d2 = d; i2 = i; }
        }
    }
    float dd0 = fmaxf(d0, 0.0f), dd1 = fmaxf(d1, 0.0f), dd2 = fmaxf(d2, 0.0f);
    float w0 = 1.0f / (dd0 + 1e-8f);
    float w1 = 1.0f / (dd1 + 1e-8f);
    float w2 = 1.0f / (dd2 + 1e-8f);
    float wsum = w0 + w1 + w2;
    w0 /= wsum; w1 /= wsum; w2 /= wsum;
    size_t ob = (size_t)t * 3;
    idx[ob + 0] = i0; idx[ob + 1] = i1; idx[ob + 2] = i2;
    w[ob + 0] = w0; w[ob + 1] = w1; w[ob + 2] = w2;
}

// -------- gather + concat: out[b,c,n] = c<C1 ? f1[b,c,n] : interp --------
__global__ void concat_interp_kernel(const float* __restrict__ f1, // [B,C1,N1]
                                     const float* __restrict__ x2, // [B,C2,N2]
                                     const int*   __restrict__ idx,
                                     const float* __restrict__ w,
                                     float* __restrict__ out,      // [B,C1+C2,N1]
                                     int C1, int C2, int N1, int N2) {
    int n = blockIdx.x * blockDim.x + threadIdx.x;
    int c = blockIdx.y;
    int b = blockIdx.z;
    if (n >= N1) return;
    int C = C1 + C2;
    float v;
    if (c < C1) {
        v = f1[((size_t)b * C1 + c) * N1 + n];
    } else {
        int c2 = c - C1;
        size_t base = ((size_t)b * N1 + n) * 3;
        const float* x2b = x2 + ((size_t)b * C2 + c2) * N2;
        v = x2b[idx[base + 0]] * w[base + 0]
          + x2b[idx[base + 1]] * w[base + 1]
          + x2b[idx[base + 2]] * w[base + 2];
    }
    out[((size_t)b * C + c) * N1 + n] = v;
}

// ------------- tiled GEMM + BN + ReLU: Y[b,o,n] = relu(g[o]*(W X) + b[o]) -------------
#define TO 32
#define TN 64
#define BK 16
__global__ __launch_bounds__(256) void conv_bn_relu_kernel(
    const float* __restrict__ X,  // [B,Cin,N]
    const float* __restrict__ W,  // [Cout,Cin]
    const float* __restrict__ g,
    const float* __restrict__ bv,
    float* __restrict__ Y,        // [B,Cout,N]
    int Cin, int Cout, int N) {
    __shared__ float Ws[BK][TO];
    __shared__ float Xs[BK][TN];
    int b = blockIdx.z;
    int oBase = blockIdx.y * TO;
    int nBase = blockIdx.x * TN;
    int tid = threadIdx.x;
    int tx = tid & 15;   // n
    int ty = tid >> 4;   // o
    float acc[2][4] = {{0.f, 0.f, 0.f, 0.f}, {0.f, 0.f, 0.f, 0.f}};
    const float* Xb = X + (size_t)b * Cin * N;
    for (int k0 = 0; k0 < Cin; k0 += BK) {
        for (int t = tid; t < TO * BK; t += 256) {
            int o = t / BK, kk = t % BK;
            Ws[kk][o] = W[(size_t)(oBase + o) * Cin + k0 + kk];
        }
        for (int t = tid; t < BK * TN; t += 256) {
            int kk = t / TN, nn = t % TN;
            Xs[kk][nn] = Xb[(size_t)(k0 + kk) * N + nBase + nn];
        }
        __syncthreads();
#pragma unroll
        for (int kk = 0; kk < BK; ++kk) {
            float w0 = Ws[kk][ty * 2 + 0];
            float w1 = Ws[kk][ty * 2 + 1];
            float4 xv = *reinterpret_cast<const float4*>(&Xs[kk][tx * 4]);
            acc[0][0] = fmaf(w0, xv.x, acc[0][0]);
            acc[0][1] = fmaf(w0, xv.y, acc[0][1]);
            acc[0][2] = fmaf(w0, xv.z, acc[0][2]);
            acc[0][3] = fmaf(w0, xv.w, acc[0][3]);
            acc[1][0] = fmaf(w1, xv.x, acc[1][0]);
            acc[1][1] = fmaf(w1, xv.y, acc[1][1]);
            acc[1][2] = fmaf(w1, xv.z, acc[1][2]);
            acc[1][3] = fmaf(w1, xv.w, acc[1][3]);
        }
        __syncthreads();
    }
#pragma unroll
    for (int r = 0; r < 2; ++r) {
        int o = oBase + ty * 2 + r;
        float gg = g[o], bb = bv[o];
        float4 st;
        st.x = fmaxf(fmaf(acc[r][0], gg, bb), 0.0f);
        st.y = fmaxf(fmaf(acc[r][1], gg, bb), 0.0f);
        st.z = fmaxf(fmaf(acc[r][2], gg, bb), 0.0f);
        st.w = fmaxf(fmaf(acc[r][3], gg, bb), 0.0f);
        *reinterpret_cast<float4*>(&Y[((size_t)b * Cout + o) * N + nBase + tx * 4]) = st;
    }
}

extern "C" void kernel_launch(void* const* d_in, const int* in_sizes, int n_in,
                              void* d_out, int out_size, void* d_ws, size_t ws_size,
                              hipStream_t stream) {
    const int B = 8;
    const int Ns[5]  = {8192, 2048, 512, 128, 32};
    const int CHs[5] = {32, 64, 128, 256, 512};

    const float* p[5];
    const float* f[5];
    for (int i = 0; i < 5; ++i) {
        p[i] = (const float*)d_in[2 * i];
        f[i] = (const float*)d_in[2 * i + 1];
    }

    float* ws = (float*)d_ws;
    int*   knn_idx = (int*)ws;                       // 196608
    float* knn_w   = ws + 196608;                    // 196608
    float* concat  = ws + 2 * 196608;                // 6291456 floats
    // partial kNN buffers alias the concat region (used strictly before it)
    float* part_d  = concat;                         // up to 8*8192*8*3 = 1572864
    int*   part_i  = (int*)(concat + 1572864);       // 1572864
    float* bufA    = concat + 6291456;               // 2097152
    float* out0    = bufA + 2097152;                 // 262144
    float* out1    = out0 + 262144;                  // 524288
    float* out2    = out1 + 524288;                  // 1048576
    float* outs[4] = {out0, out1, out2, (float*)d_out};

    for (int s = 0; s < 4; ++s) {
        int lvl = 3 - s;
        int N1 = Ns[lvl], N2 = Ns[lvl + 1];
        int C1 = CHs[lvl];
        int C2 = (s == 0) ? CHs[4] : CHs[lvl + 1];
        int Cin = C1 + C2;
        int Cout = C1;
        const float* x2 = (s == 0) ? f[4] : outs[s - 1];
        const float* wa = (const float*)d_in[10 + s * 6 + 0];
        const float* ga = (const float*)d_in[10 + s * 6 + 1];
        const float* ba = (const float*)d_in[10 + s * 6 + 2];
        const float* wb = (const float*)d_in[10 + s * 6 + 3];
        const float* gb = (const float*)d_in[10 + s * 6 + 4];
        const float* bb = (const float*)d_in[10 + s * 6 + 5];

        // ---- kNN: chunked over N2 for occupancy ----
        int nchunk = (N2 >= 2048) ? 8 : (N2 >= 512) ? 8 : (N2 >= 128) ? 4 : 1;
        int chunk = N2 / nchunk;
        dim3 kg((N1 + 255) / 256, B, nchunk);
        size_t lds = (size_t)chunk * sizeof(float4);
        knn_chunk_kernel<<<kg, 256, lds, stream>>>(p[lvl], p[lvl + 1],
                                                   part_d, part_i, N1, N2, chunk, nchunk);
        int total = B * N1;
        knn_merge_kernel<<<(total + 255) / 256, 256, 0, stream>>>(part_d, part_i,
                                                                  knn_idx, knn_w, total, nchunk);

        // ---- gather + concat ----
        dim3 cg((N1 + 255) / 256, Cin, B);
        concat_interp_kernel<<<cg, 256, 0, stream>>>(f[lvl], x2, knn_idx, knn_w,
                                                     concat, C1, C2, N1, N2);

        // ---- conv_a, conv_b ----
        dim3 ag(N1 / TN, Cout / TO, B);
        conv_bn_relu_kernel<<<ag, 256, 0, stream>>>(concat, wa, ga, ba, bufA, Cin, Cout, N1);
        conv_bn_relu_kernel<<<ag, 256, 0, stream>>>(bufA, wb, gb, bb, outs[s], Cout, Cout, N1);
    }
}

// Round 3
// 291.387 us; speedup vs baseline: 1.9227x; 1.3551x over previous
//
#include <hip/hip_runtime.h>

#define KNN_INF 3.0e38f

// ---- kNN over a chunk of the sparse set: partial top-3 per (dense point, chunk) ----
__global__ void knn_chunk_kernel(const float* __restrict__ p1, // [B,N1,3]
                                 const float* __restrict__ p2, // [B,N2,3]
                                 float* __restrict__ pd,       // [B,N1,nchunk,3]
                                 int*   __restrict__ pi,       // [B,N1,nchunk,3]
                                 int N1, int N2, int chunk, int nchunk) {
    extern __shared__ float4 sm4[]; // chunk entries: x,y,z,|p|^2
    int z = blockIdx.z;
    int b = blockIdx.y;
    int m0 = z * chunk;
    const float* p2b = p2 + ((size_t)b * N2 + m0) * 3;
    for (int m = threadIdx.x; m < chunk; m += blockDim.x) {
        float x = p2b[m * 3 + 0], y = p2b[m * 3 + 1], zz = p2b[m * 3 + 2];
        sm4[m] = make_float4(x, y, zz, x * x + y * y + zz * zz);
    }
    __syncthreads();
    int n = blockIdx.x * blockDim.x + threadIdx.x;
    if (n >= N1) return;
    const float* p1b = p1 + ((size_t)b * N1 + n) * 3;
    float px = p1b[0], py = p1b[1], pz = p1b[2];
    float s1 = px * px + py * py + pz * pz;
    float d0 = KNN_INF, d1 = KNN_INF, d2 = KNN_INF;
    int i0 = 0, i1 = 0, i2 = 0;
    for (int m = 0; m < chunk; ++m) {
        float4 q = sm4[m];
        float dot = px * q.x + py * q.y + pz * q.z;
        float d = fmaf(-2.0f, dot, s1 + q.w);
        if (d < d2) {
            if (d < d1) {
                d2 = d1; i2 = i1;
                if (d < d0) { d1 = d0; i1 = i0; d0 = d; i0 = m; }
                else        { d1 = d;  i1 = m; }
            } else { d2 = d; i2 = m; }
        }
    }
    size_t base = (((size_t)b * N1 + n) * nchunk + z) * 3;
    pd[base + 0] = d0; pd[base + 1] = d1; pd[base + 2] = d2;
    pi[base + 0] = m0 + i0; pi[base + 1] = m0 + i1; pi[base + 2] = m0 + i2;
}

// ---- merge partial top-3s (in global-index order) + compute weights ----
__global__ void knn_merge_kernel(const float* __restrict__ pd,
                                 const int*   __restrict__ pi,
                                 int*   __restrict__ idx,  // [B*N1,3]
                                 float* __restrict__ w,    // [B*N1,3]
                                 int total, int nchunk) {
    int t = blockIdx.x * blockDim.x + threadIdx.x;
    if (t >= total) return;
    float d0 = KNN_INF, d1 = KNN_INF, d2 = KNN_INF;
    int i0 = 0, i1 = 0, i2 = 0;
    size_t base = (size_t)t * nchunk * 3;
    for (int c = 0; c < nchunk * 3; ++c) {
        float d = pd[base + c];
        int   i = pi[base + c];
        if (d < d2) {
            if (d < d1) {
                d2 = d1; i2 = i1;
                if (d < d0) { d1 = d0; i1 = i0; d0 = d; i0 = i; }
                else        { d1 = d;  i1 = i; }
            } else { d2 = d; i2 = i; }
        }
    }
    float dd0 = fmaxf(d0, 0.0f), dd1 = fmaxf(d1, 0.0f), dd2 = fmaxf(d2, 0.0f);
    float w0 = 1.0f / (dd0 + 1e-8f);
    float w1 = 1.0f / (dd1 + 1e-8f);
    float w2 = 1.0f / (dd2 + 1e-8f);
    float wsum = w0 + w1 + w2;
    w0 /= wsum; w1 /= wsum; w2 /= wsum;
    size_t ob = (size_t)t * 3;
    idx[ob + 0] = i0; idx[ob + 1] = i1; idx[ob + 2] = i2;
    w[ob + 0] = w0; w[ob + 1] = w1; w[ob + 2] = w2;
}

// -------- gather + concat: out[b,c,n] = c<C1 ? f1[b,c,n] : interp --------
__global__ void concat_interp_kernel(const float* __restrict__ f1, // [B,C1,N1]
                                     const float* __restrict__ x2, // [B,C2,N2]
                                     const int*   __restrict__ idx,
                                     const float* __restrict__ w,
                                     float* __restrict__ out,      // [B,C1+C2,N1]
                                     int C1, int C2, int N1, int N2) {
    int n = blockIdx.x * blockDim.x + threadIdx.x;
    int c = blockIdx.y;
    int b = blockIdx.z;
    if (n >= N1) return;
    int C = C1 + C2;
    float v;
    if (c < C1) {
        v = f1[((size_t)b * C1 + c) * N1 + n];
    } else {
        int c2 = c - C1;
        size_t base = ((size_t)b * N1 + n) * 3;
        const float* x2b = x2 + ((size_t)b * C2 + c2) * N2;
        v = x2b[idx[base + 0]] * w[base + 0]
          + x2b[idx[base + 1]] * w[base + 1]
          + x2b[idx[base + 2]] * w[base + 2];
    }
    out[((size_t)b * C + c) * N1 + n] = v;
}

// ------------- tiled GEMM (+BN+ReLU or partial): split-K over blockIdx.z -------------
#define TO 32
#define TN 64
#define BK 16
template<bool PARTIAL>
__global__ __launch_bounds__(256) void conv_gemm_kernel(
    const float* __restrict__ X,  // [B,Cin,N]
    const float* __restrict__ W,  // [Cout,Cin]
    const float* __restrict__ g,
    const float* __restrict__ bv,
    float* __restrict__ Y,        // PARTIAL ? [nsplit,B,Cout,N] : [B,Cout,N]
    int Cin, int Cout, int N, int chunk) {
    __shared__ float Ws[BK][TO];
    __shared__ float Xs[BK][TN];
    int zb = blockIdx.z;         // split*B + b
    int b = zb & 7;              // B == 8
    int split = zb >> 3;
    int kBase = split * chunk;
    int oBase = blockIdx.y * TO;
    int nBase = blockIdx.x * TN;
    int tid = threadIdx.x;
    int tx = tid & 15;   // n
    int ty = tid >> 4;   // o
    float acc[2][4] = {{0.f, 0.f, 0.f, 0.f}, {0.f, 0.f, 0.f, 0.f}};
    const float* Xb = X + (size_t)b * Cin * N;
    for (int k0 = kBase; k0 < kBase + chunk; k0 += BK) {
        for (int t = tid; t < TO * BK; t += 256) {
            int o = t / BK, kk = t % BK;
            Ws[kk][o] = W[(size_t)(oBase + o) * Cin + k0 + kk];
        }
        for (int t = tid; t < BK * TN; t += 256) {
            int kk = t / TN, nn = t % TN;
            Xs[kk][nn] = Xb[(size_t)(k0 + kk) * N + nBase + nn];
        }
        __syncthreads();
#pragma unroll
        for (int kk = 0; kk < BK; ++kk) {
            float w0 = Ws[kk][ty * 2 + 0];
            float w1 = Ws[kk][ty * 2 + 1];
            float4 xv = *reinterpret_cast<const float4*>(&Xs[kk][tx * 4]);
            acc[0][0] = fmaf(w0, xv.x, acc[0][0]);
            acc[0][1] = fmaf(w0, xv.y, acc[0][1]);
            acc[0][2] = fmaf(w0, xv.z, acc[0][2]);
            acc[0][3] = fmaf(w0, xv.w, acc[0][3]);
            acc[1][0] = fmaf(w1, xv.x, acc[1][0]);
            acc[1][1] = fmaf(w1, xv.y, acc[1][1]);
            acc[1][2] = fmaf(w1, xv.z, acc[1][2]);
            acc[1][3] = fmaf(w1, xv.w, acc[1][3]);
        }
        __syncthreads();
    }
#pragma unroll
    for (int r = 0; r < 2; ++r) {
        int o = oBase + ty * 2 + r;
        float4 st;
        if (PARTIAL) {
            st.x = acc[r][0]; st.y = acc[r][1]; st.z = acc[r][2]; st.w = acc[r][3];
            *reinterpret_cast<float4*>(&Y[((size_t)zb * Cout + o) * N + nBase + tx * 4]) = st;
        } else {
            float gg = g[o], bb = bv[o];
            st.x = fmaxf(fmaf(acc[r][0], gg, bb), 0.0f);
            st.y = fmaxf(fmaf(acc[r][1], gg, bb), 0.0f);
            st.z = fmaxf(fmaf(acc[r][2], gg, bb), 0.0f);
            st.w = fmaxf(fmaf(acc[r][3], gg, bb), 0.0f);
            *reinterpret_cast<float4*>(&Y[((size_t)b * Cout + o) * N + nBase + tx * 4]) = st;
        }
    }
}

// ---- sum split-K partials (fixed order -> deterministic) + BN + ReLU ----
__global__ void reduce_bn_relu_kernel(const float* __restrict__ part, // [nsplit,B,Cout,N]
                                      const float* __restrict__ g,
                                      const float* __restrict__ bv,
                                      float* __restrict__ Y,          // [B,Cout,N]
                                      int Cout, int N, int total4, int nsplit, int stride4) {
    int t = blockIdx.x * blockDim.x + threadIdx.x;
    if (t >= total4) return;
    const float4* p4 = reinterpret_cast<const float4*>(part);
    float4 a = p4[t];
    for (int s = 1; s < nsplit; ++s) {
        float4 v = p4[t + (size_t)s * stride4];
        a.x += v.x; a.y += v.y; a.z += v.z; a.w += v.w;
    }
    int o = ((t * 4) / N) % Cout;   // N % 4 == 0 -> all 4 lanes share o
    float gg = g[o], bb = bv[o];
    float4 st;
    st.x = fmaxf(fmaf(a.x, gg, bb), 0.0f);
    st.y = fmaxf(fmaf(a.y, gg, bb), 0.0f);
    st.z = fmaxf(fmaf(a.z, gg, bb), 0.0f);
    st.w = fmaxf(fmaf(a.w, gg, bb), 0.0f);
    reinterpret_cast<float4*>(Y)[t] = st;
}

static void launch_conv(const float* X, const float* W, const float* g, const float* bv,
                        float* Y, float* part, int Cin, int Cout, int N, int B,
                        int nsplit, hipStream_t stream) {
    int chunk = Cin / nsplit;
    dim3 grid(N / TN, Cout / TO, B * nsplit);
    if (nsplit == 1) {
        conv_gemm_kernel<false><<<grid, 256, 0, stream>>>(X, W, g, bv, Y, Cin, Cout, N, chunk);
    } else {
        conv_gemm_kernel<true><<<grid, 256, 0, stream>>>(X, W, g, bv, part, Cin, Cout, N, chunk);
        int total4 = B * Cout * N / 4;
        reduce_bn_relu_kernel<<<(total4 + 255) / 256, 256, 0, stream>>>(
            part, g, bv, Y, Cout, N, total4, nsplit, total4);
    }
}

extern "C" void kernel_launch(void* const* d_in, const int* in_sizes, int n_in,
                              void* d_out, int out_size, void* d_ws, size_t ws_size,
                              hipStream_t stream) {
    const int B = 8;
    const int Ns[5]  = {8192, 2048, 512, 128, 32};
    const int CHs[5] = {32, 64, 128, 256, 512};

    const float* p[5];
    const float* f[5];
    for (int i = 0; i < 5; ++i) {
        p[i] = (const float*)d_in[2 * i];
        f[i] = (const float*)d_in[2 * i + 1];
    }

    float* ws = (float*)d_ws;
    int*   knn_idx = (int*)ws;                       // 196608
    float* knn_w   = ws + 196608;                    // 196608
    float* concat  = ws + 2 * 196608;                // 6291456 floats
    // partial kNN buffers alias the concat region (used strictly before it)
    float* part_d  = concat;                         // up to 1572864
    int*   part_i  = (int*)(concat + 1572864);       // 1572864
    float* bufA    = concat + 6291456;               // 2097152
    float* out0    = bufA + 2097152;                 // 262144
    float* out1    = out0 + 262144;                  // 524288
    float* out2    = out1 + 524288;                  // 1048576
    float* gpart   = out2 + 1048576;                 // up to 2097152 (split-K partials)
    float* outs[4] = {out0, out1, out2, (float*)d_out};

    // split-K factors per stage (conv_a, conv_b); chunks stay multiples of BK
    const int nsA[4] = {6, 3, 2, 1};   // Cin: 768->128, 384->128, 192->96, 96(grid already 1024)
    const int nsB[4] = {4, 2, 1, 1};   // Cin: 256->64, 128->64, 64, 32

    for (int s = 0; s < 4; ++s) {
        int lvl = 3 - s;
        int N1 = Ns[lvl], N2 = Ns[lvl + 1];
        int C1 = CHs[lvl];
        int C2 = (s == 0) ? CHs[4] : CHs[lvl + 1];
        int Cin = C1 + C2;
        int Cout = C1;
        const float* x2 = (s == 0) ? f[4] : outs[s - 1];
        const float* wa = (const float*)d_in[10 + s * 6 + 0];
        const float* ga = (const float*)d_in[10 + s * 6 + 1];
        const float* ba = (const float*)d_in[10 + s * 6 + 2];
        const float* wb = (const float*)d_in[10 + s * 6 + 3];
        const float* gb = (const float*)d_in[10 + s * 6 + 4];
        const float* bb = (const float*)d_in[10 + s * 6 + 5];

        // ---- kNN: chunked over N2 for occupancy ----
        int nchunk = (N2 >= 512) ? 8 : (N2 >= 128) ? 4 : 1;
        int chunk = N2 / nchunk;
        dim3 kg((N1 + 255) / 256, B, nchunk);
        size_t lds = (size_t)chunk * sizeof(float4);
        knn_chunk_kernel<<<kg, 256, lds, stream>>>(p[lvl], p[lvl + 1],
                                                   part_d, part_i, N1, N2, chunk, nchunk);
        int total = B * N1;
        knn_merge_kernel<<<(total + 255) / 256, 256, 0, stream>>>(part_d, part_i,
                                                                  knn_idx, knn_w, total, nchunk);

        // ---- gather + concat ----
        dim3 cg((N1 + 255) / 256, Cin, B);
        concat_interp_kernel<<<cg, 256, 0, stream>>>(f[lvl], x2, knn_idx, knn_w,
                                                     concat, C1, C2, N1, N2);

        // ---- conv_a, conv_b (split-K where the grid would be tiny) ----
        launch_conv(concat, wa, ga, ba, bufA, gpart, Cin, Cout, N1, B, nsA[s], stream);
        launch_conv(bufA, wb, gb, bb, outs[s], gpart, Cout, Cout, N1, B, nsB[s], stream);
    }
}

// Round 4
// 290.810 us; speedup vs baseline: 1.9265x; 1.0020x over previous
//
#include <hip/hip_runtime.h>

#define KNN_INF 3.0e38f

// ---- kNN over a chunk of the sparse set: partial top-3 per (dense point, chunk) ----
// Branchless top-3 insert: 3 v_cmp + 10 v_cndmask per candidate, no divergence.
__global__ void knn_chunk_kernel(const float* __restrict__ p1, // [B,N1,3]
                                 const float* __restrict__ p2, // [B,N2,3]
                                 float* __restrict__ pd,       // [B,N1,nchunk,3]
                                 int*   __restrict__ pi,       // [B,N1,nchunk,3]
                                 int N1, int N2, int chunk, int nchunk) {
    extern __shared__ float4 sm4[]; // chunk entries: x,y,z,|p|^2
    int z = blockIdx.z;
    int b = blockIdx.y;
    int m0 = z * chunk;
    const float* p2b = p2 + ((size_t)b * N2 + m0) * 3;
    for (int m = threadIdx.x; m < chunk; m += blockDim.x) {
        float x = p2b[m * 3 + 0], y = p2b[m * 3 + 1], zz = p2b[m * 3 + 2];
        sm4[m] = make_float4(x, y, zz, x * x + y * y + zz * zz);
    }
    __syncthreads();
    int n = blockIdx.x * blockDim.x + threadIdx.x;
    if (n >= N1) return;
    const float* p1b = p1 + ((size_t)b * N1 + n) * 3;
    float px = p1b[0], py = p1b[1], pz = p1b[2];
    float s1 = px * px + py * py + pz * pz;
    float d0 = KNN_INF, d1 = KNN_INF, d2 = KNN_INF;
    int i0 = 0, i1 = 0, i2 = 0;
#pragma unroll 4
    for (int m = 0; m < chunk; ++m) {
        float4 q = sm4[m];
        float dot = px * q.x + py * q.y + pz * q.z;       // same bits as previous round
        float d = fmaf(-2.0f, dot, s1 + q.w);             // same bits as previous round
        bool c2 = d < d2;
        bool c1 = d < d1;
        bool c0 = d < d0;
        // shift-down sorted insert; read-before-write order d2 <- d1 <- d0
        d2 = c1 ? d1 : (c2 ? d : d2);
        i2 = c1 ? i1 : (c2 ? m : i2);
        d1 = c0 ? d0 : (c1 ? d : d1);
        i1 = c0 ? i0 : (c1 ? m : i1);
        d0 = c0 ? d  : d0;
        i0 = c0 ? m  : i0;
    }
    size_t base = (((size_t)b * N1 + n) * nchunk + z) * 3;
    pd[base + 0] = d0; pd[base + 1] = d1; pd[base + 2] = d2;
    pi[base + 0] = m0 + i0; pi[base + 1] = m0 + i1; pi[base + 2] = m0 + i2;
}

// ---- merge partial top-3s (in global-index order) + compute weights ----
__global__ void knn_merge_kernel(const float* __restrict__ pd,
                                 const int*   __restrict__ pi,
                                 int*   __restrict__ idx,  // [B*N1,3]
                                 float* __restrict__ w,    // [B*N1,3]
                                 int total, int nchunk) {
    int t = blockIdx.x * blockDim.x + threadIdx.x;
    if (t >= total) return;
    float d0 = KNN_INF, d1 = KNN_INF, d2 = KNN_INF;
    int i0 = 0, i1 = 0, i2 = 0;
    size_t base = (size_t)t * nchunk * 3;
    for (int c = 0; c < nchunk * 3; ++c) {
        float d = pd[base + c];
        int   i = pi[base + c];
        bool c2 = d < d2;
        bool c1 = d < d1;
        bool c0 = d < d0;
        d2 = c1 ? d1 : (c2 ? d : d2);
        i2 = c1 ? i1 : (c2 ? i : i2);
        d1 = c0 ? d0 : (c1 ? d : d1);
        i1 = c0 ? i0 : (c1 ? i : i1);
        d0 = c0 ? d  : d0;
        i0 = c0 ? i  : i0;
    }
    float dd0 = fmaxf(d0, 0.0f), dd1 = fmaxf(d1, 0.0f), dd2 = fmaxf(d2, 0.0f);
    float w0 = 1.0f / (dd0 + 1e-8f);
    float w1 = 1.0f / (dd1 + 1e-8f);
    float w2 = 1.0f / (dd2 + 1e-8f);
    float wsum = w0 + w1 + w2;
    w0 /= wsum; w1 /= wsum; w2 /= wsum;
    size_t ob = (size_t)t * 3;
    idx[ob + 0] = i0; idx[ob + 1] = i1; idx[ob + 2] = i2;
    w[ob + 0] = w0; w[ob + 1] = w1; w[ob + 2] = w2;
}

// -------- gather + concat: out[b,c,n] = c<C1 ? f1[b,c,n] : interp --------
__global__ void concat_interp_kernel(const float* __restrict__ f1, // [B,C1,N1]
                                     const float* __restrict__ x2, // [B,C2,N2]
                                     const int*   __restrict__ idx,
                                     const float* __restrict__ w,
                                     float* __restrict__ out,      // [B,C1+C2,N1]
                                     int C1, int C2, int N1, int N2) {
    int n = blockIdx.x * blockDim.x + threadIdx.x;
    int c = blockIdx.y;
    int b = blockIdx.z;
    if (n >= N1) return;
    int C = C1 + C2;
    float v;
    if (c < C1) {
        v = f1[((size_t)b * C1 + c) * N1 + n];
    } else {
        int c2 = c - C1;
        size_t base = ((size_t)b * N1 + n) * 3;
        const float* x2b = x2 + ((size_t)b * C2 + c2) * N2;
        v = x2b[idx[base + 0]] * w[base + 0]
          + x2b[idx[base + 1]] * w[base + 1]
          + x2b[idx[base + 2]] * w[base + 2];
    }
    out[((size_t)b * C + c) * N1 + n] = v;
}

// ------------- tiled GEMM (+BN+ReLU or partial): split-K over blockIdx.z -------------
#define TO 32
#define TN 64
#define BK 16
template<bool PARTIAL>
__global__ __launch_bounds__(256) void conv_gemm_kernel(
    const float* __restrict__ X,  // [B,Cin,N]
    const float* __restrict__ W,  // [Cout,Cin]
    const float* __restrict__ g,
    const float* __restrict__ bv,
    float* __restrict__ Y,        // PARTIAL ? [nsplit,B,Cout,N] : [B,Cout,N]
    int Cin, int Cout, int N, int chunk) {
    __shared__ float Ws[BK][TO];
    __shared__ float Xs[BK][TN];
    int zb = blockIdx.z;         // split*B + b
    int b = zb & 7;              // B == 8
    int split = zb >> 3;
    int kBase = split * chunk;
    int oBase = blockIdx.y * TO;
    int nBase = blockIdx.x * TN;
    int tid = threadIdx.x;
    int tx = tid & 15;   // n
    int ty = tid >> 4;   // o
    float acc[2][4] = {{0.f, 0.f, 0.f, 0.f}, {0.f, 0.f, 0.f, 0.f}};
    const float* Xb = X + (size_t)b * Cin * N;
    for (int k0 = kBase; k0 < kBase + chunk; k0 += BK) {
        for (int t = tid; t < TO * BK; t += 256) {
            int o = t / BK, kk = t % BK;
            Ws[kk][o] = W[(size_t)(oBase + o) * Cin + k0 + kk];
        }
        for (int t = tid; t < BK * TN; t += 256) {
            int kk = t / TN, nn = t % TN;
            Xs[kk][nn] = Xb[(size_t)(k0 + kk) * N + nBase + nn];
        }
        __syncthreads();
#pragma unroll
        for (int kk = 0; kk < BK; ++kk) {
            float w0 = Ws[kk][ty * 2 + 0];
            float w1 = Ws[kk][ty * 2 + 1];
            float4 xv = *reinterpret_cast<const float4*>(&Xs[kk][tx * 4]);
            acc[0][0] = fmaf(w0, xv.x, acc[0][0]);
            acc[0][1] = fmaf(w0, xv.y, acc[0][1]);
            acc[0][2] = fmaf(w0, xv.z, acc[0][2]);
            acc[0][3] = fmaf(w0, xv.w, acc[0][3]);
            acc[1][0] = fmaf(w1, xv.x, acc[1][0]);
            acc[1][1] = fmaf(w1, xv.y, acc[1][1]);
            acc[1][2] = fmaf(w1, xv.z, acc[1][2]);
            acc[1][3] = fmaf(w1, xv.w, acc[1][3]);
        }
        __syncthreads();
    }
#pragma unroll
    for (int r = 0; r < 2; ++r) {
        int o = oBase + ty * 2 + r;
        float4 st;
        if (PARTIAL) {
            st.x = acc[r][0]; st.y = acc[r][1]; st.z = acc[r][2]; st.w = acc[r][3];
            *reinterpret_cast<float4*>(&Y[((size_t)zb * Cout + o) * N + nBase + tx * 4]) = st;
        } else {
            float gg = g[o], bb = bv[o];
            st.x = fmaxf(fmaf(acc[r][0], gg, bb), 0.0f);
            st.y = fmaxf(fmaf(acc[r][1], gg, bb), 0.0f);
            st.z = fmaxf(fmaf(acc[r][2], gg, bb), 0.0f);
            st.w = fmaxf(fmaf(acc[r][3], gg, bb), 0.0f);
            *reinterpret_cast<float4*>(&Y[((size_t)b * Cout + o) * N + nBase + tx * 4]) = st;
        }
    }
}

// ---- sum split-K partials (fixed order -> deterministic) + BN + ReLU ----
__global__ void reduce_bn_relu_kernel(const float* __restrict__ part, // [nsplit,B,Cout,N]
                                      const float* __restrict__ g,
                                      const float* __restrict__ bv,
                                      float* __restrict__ Y,          // [B,Cout,N]
                                      int Cout, int N, int total4, int nsplit, int stride4) {
    int t = blockIdx.x * blockDim.x + threadIdx.x;
    if (t >= total4) return;
    const float4* p4 = reinterpret_cast<const float4*>(part);
    float4 a = p4[t];
    for (int s = 1; s < nsplit; ++s) {
        float4 v = p4[t + (size_t)s * stride4];
        a.x += v.x; a.y += v.y; a.z += v.z; a.w += v.w;
    }
    int o = ((t * 4) / N) % Cout;   // N % 4 == 0 -> all 4 lanes share o
    float gg = g[o], bb = bv[o];
    float4 st;
    st.x = fmaxf(fmaf(a.x, gg, bb), 0.0f);
    st.y = fmaxf(fmaf(a.y, gg, bb), 0.0f);
    st.z = fmaxf(fmaf(a.z, gg, bb), 0.0f);
    st.w = fmaxf(fmaf(a.w, gg, bb), 0.0f);
    reinterpret_cast<float4*>(Y)[t] = st;
}

static void launch_conv(const float* X, const float* W, const float* g, const float* bv,
                        float* Y, float* part, int Cin, int Cout, int N, int B,
                        int nsplit, hipStream_t stream) {
    int chunk = Cin / nsplit;
    dim3 grid(N / TN, Cout / TO, B * nsplit);
    if (nsplit == 1) {
        conv_gemm_kernel<false><<<grid, 256, 0, stream>>>(X, W, g, bv, Y, Cin, Cout, N, chunk);
    } else {
        conv_gemm_kernel<true><<<grid, 256, 0, stream>>>(X, W, g, bv, part, Cin, Cout, N, chunk);
        int total4 = B * Cout * N / 4;
        reduce_bn_relu_kernel<<<(total4 + 255) / 256, 256, 0, stream>>>(
            part, g, bv, Y, Cout, N, total4, nsplit, total4);
    }
}

extern "C" void kernel_launch(void* const* d_in, const int* in_sizes, int n_in,
                              void* d_out, int out_size, void* d_ws, size_t ws_size,
                              hipStream_t stream) {
    const int B = 8;
    const int Ns[5]  = {8192, 2048, 512, 128, 32};
    const int CHs[5] = {32, 64, 128, 256, 512};

    const float* p[5];
    const float* f[5];
    for (int i = 0; i < 5; ++i) {
        p[i] = (const float*)d_in[2 * i];
        f[i] = (const float*)d_in[2 * i + 1];
    }

    float* ws = (float*)d_ws;
    int*   knn_idx = (int*)ws;                       // 196608
    float* knn_w   = ws + 196608;                    // 196608
    float* concat  = ws + 2 * 196608;                // 6291456 floats
    // partial kNN buffers alias the concat region (used strictly before it)
    float* part_d  = concat;                         // up to 1572864
    int*   part_i  = (int*)(concat + 1572864);       // 1572864
    float* bufA    = concat + 6291456;               // 2097152
    float* out0    = bufA + 2097152;                 // 262144
    float* out1    = out0 + 262144;                  // 524288
    float* out2    = out1 + 524288;                  // 1048576
    float* gpart   = out2 + 1048576;                 // up to 2097152 (split-K partials)
    float* outs[4] = {out0, out1, out2, (float*)d_out};

    // split-K factors per stage (conv_a, conv_b); chunks stay multiples of BK
    const int nsA[4] = {6, 3, 2, 1};
    const int nsB[4] = {4, 2, 1, 1};

    for (int s = 0; s < 4; ++s) {
        int lvl = 3 - s;
        int N1 = Ns[lvl], N2 = Ns[lvl + 1];
        int C1 = CHs[lvl];
        int C2 = (s == 0) ? CHs[4] : CHs[lvl + 1];
        int Cin = C1 + C2;
        int Cout = C1;
        const float* x2 = (s == 0) ? f[4] : outs[s - 1];
        const float* wa = (const float*)d_in[10 + s * 6 + 0];
        const float* ga = (const float*)d_in[10 + s * 6 + 1];
        const float* ba = (const float*)d_in[10 + s * 6 + 2];
        const float* wb = (const float*)d_in[10 + s * 6 + 3];
        const float* gb = (const float*)d_in[10 + s * 6 + 4];
        const float* bb = (const float*)d_in[10 + s * 6 + 5];

        // ---- kNN: chunked over N2 for occupancy ----
        int nchunk = (N2 >= 512) ? 8 : (N2 >= 128) ? 4 : 1;
        int chunk = N2 / nchunk;
        dim3 kg((N1 + 255) / 256, B, nchunk);
        size_t lds = (size_t)chunk * sizeof(float4);
        knn_chunk_kernel<<<kg, 256, lds, stream>>>(p[lvl], p[lvl + 1],
                                                   part_d, part_i, N1, N2, chunk, nchunk);
        int total = B * N1;
        knn_merge_kernel<<<(total + 255) / 256, 256, 0, stream>>>(part_d, part_i,
                                                                  knn_idx, knn_w, total, nchunk);

        // ---- gather + concat ----
        dim3 cg((N1 + 255) / 256, Cin, B);
        concat_interp_kernel<<<cg, 256, 0, stream>>>(f[lvl], x2, knn_idx, knn_w,
                                                     concat, C1, C2, N1, N2);

        // ---- conv_a, conv_b (split-K where the grid would be tiny) ----
        launch_conv(concat, wa, ga, ba, bufA, gpart, Cin, Cout, N1, B, nsA[s], stream);
        launch_conv(bufA, wb, gb, bb, outs[s], gpart, Cout, Cout, N1, B, nsB[s], stream);
    }
}

// Round 5
// 231.485 us; speedup vs baseline: 2.4202x; 1.2563x over previous
//
#include <hip/hip_runtime.h>

#define KNN_INF 3.0e38f

struct KnnAll {
    const float* p1[4]; const float* p2[4];
    float* pd[4]; int* pi[4];
    int N1[4], N2[4], chunk[4], nchunk[4], nbx[4];
    int blkStart[4]; // starts of stages 1..3 at [1..3]; [0]=8 boundary handled below
    int bs1, bs2, bs3;
};

// ---- all stages' chunked kNN in one launch; branchy top-3 insert (r2-proven) ----
__global__ void knn_all_kernel(KnnAll P) {
    __shared__ float4 sm4[256];
    int bid = blockIdx.x;
    int s = (bid >= P.bs1) + (bid >= P.bs2) + (bid >= P.bs3);
    int start = (s == 0) ? 0 : (s == 1) ? P.bs1 : (s == 2) ? P.bs2 : P.bs3;
    int local = bid - start;
    int nbx = P.nbx[s];
    int bx = local % nbx;
    int rest = local / nbx;
    int b = rest & 7;          // B == 8
    int z = rest >> 3;
    int N1 = P.N1[s], N2 = P.N2[s], chunk = P.chunk[s], nchunk = P.nchunk[s];
    int m0 = z * chunk;
    const float* p2b = P.p2[s] + ((size_t)b * N2 + m0) * 3;
    for (int m = threadIdx.x; m < chunk; m += blockDim.x) {
        float x = p2b[m * 3 + 0], y = p2b[m * 3 + 1], zz = p2b[m * 3 + 2];
        sm4[m] = make_float4(x, y, zz, x * x + y * y + zz * zz);
    }
    __syncthreads();
    int n = bx * blockDim.x + threadIdx.x;
    if (n >= N1) return;
    const float* p1b = P.p1[s] + ((size_t)b * N1 + n) * 3;
    float px = p1b[0], py = p1b[1], pz = p1b[2];
    float s1 = px * px + py * py + pz * pz;
    float d0 = KNN_INF, d1 = KNN_INF, d2 = KNN_INF;
    int i0 = 0, i1 = 0, i2 = 0;
    for (int m = 0; m < chunk; ++m) {
        float4 q = sm4[m];
        float dot = px * q.x + py * q.y + pz * q.z;   // bit-identical to r2/r4
        float d = fmaf(-2.0f, dot, s1 + q.w);
        if (d < d2) {
            if (d < d1) {
                d2 = d1; i2 = i1;
                if (d < d0) { d1 = d0; i1 = i0; d0 = d; i0 = m; }
                else        { d1 = d;  i1 = m; }
            } else { d2 = d; i2 = m; }
        }
    }
    size_t base = (((size_t)b * N1 + n) * nchunk + z) * 3;
    float* pd = P.pd[s]; int* pi = P.pi[s];
    pd[base + 0] = d0; pd[base + 1] = d1; pd[base + 2] = d2;
    pi[base + 0] = m0 + i0; pi[base + 1] = m0 + i1; pi[base + 2] = m0 + i2;
}

struct MergeAll {
    const float* pd[4]; const int* pi[4];
    int* idx[4]; float* w[4];
    int nchunk[4], N1[4];
    int ts1, ts2, ts3;
};

// ---- all stages' merges in one launch ----
__global__ void knn_merge_all_kernel(MergeAll P) {
    int t = blockIdx.x * blockDim.x + threadIdx.x;
    int s = (t >= P.ts1) + (t >= P.ts2) + (t >= P.ts3);
    int start = (s == 0) ? 0 : (s == 1) ? P.ts1 : (s == 2) ? P.ts2 : P.ts3;
    int lt = t - start;
    int nchunk = P.nchunk[s];
    float d0 = KNN_INF, d1 = KNN_INF, d2 = KNN_INF;
    int i0 = 0, i1 = 0, i2 = 0;
    const float* pd = P.pd[s]; const int* pi = P.pi[s];
    size_t base = (size_t)lt * nchunk * 3;
    for (int c = 0; c < nchunk * 3; ++c) {
        float d = pd[base + c];
        int   i = pi[base + c];
        if (d < d2) {
            if (d < d1) {
                d2 = d1; i2 = i1;
                if (d < d0) { d1 = d0; i1 = i0; d0 = d; i0 = i; }
                else        { d1 = d;  i1 = i; }
            } else { d2 = d; i2 = i; }
        }
    }
    float dd0 = fmaxf(d0, 0.0f), dd1 = fmaxf(d1, 0.0f), dd2 = fmaxf(d2, 0.0f);
    float w0 = 1.0f / (dd0 + 1e-8f);
    float w1 = 1.0f / (dd1 + 1e-8f);
    float w2 = 1.0f / (dd2 + 1e-8f);
    float wsum = w0 + w1 + w2;
    w0 /= wsum; w1 /= wsum; w2 /= wsum;
    size_t ob = (size_t)lt * 3;
    P.idx[s][ob + 0] = i0; P.idx[s][ob + 1] = i1; P.idx[s][ob + 2] = i2;
    P.w[s][ob + 0] = w0; P.w[s][ob + 1] = w1; P.w[s][ob + 2] = w2;
}

// ------------- fused conv_a: X rows k<C1 from f1, else 3-pt gather-interp -------------
#define TO 32
#define TN 64
#define BK 16
template<bool PARTIAL>
__global__ __launch_bounds__(256) void conv_a_fused_kernel(
    const float* __restrict__ f1,  // [B,C1,N]
    const float* __restrict__ x2,  // [B,C2,N2]
    const int*   __restrict__ idxS,// [B*N,3]
    const float* __restrict__ wS,  // [B*N,3]
    const float* __restrict__ W,   // [Cout,Cin]
    const float* __restrict__ g,
    const float* __restrict__ bv,
    float* __restrict__ Y,         // PARTIAL ? [nsplit,B,Cout,N] : [B,Cout,N]
    int C1, int C2, int N, int N2, int Cout, int chunk) {
    __shared__ float Ws[BK][TO];
    __shared__ float Xs[BK][TN];
    int Cin = C1 + C2;
    int zb = blockIdx.z;
    int b = zb & 7;
    int split = zb >> 3;
    int kBase = split * chunk;
    int oBase = blockIdx.y * TO;
    int nBase = blockIdx.x * TN;
    int tid = threadIdx.x;
    int tx = tid & 15;
    int ty = tid >> 4;
    // per-thread fixed tile column for the X loader
    int nn = tid & 63;
    int kk0 = tid >> 6;      // 0..3
    int n = nBase + nn;
    size_t gb = ((size_t)b * N + n) * 3;
    int j0 = idxS[gb + 0], j1 = idxS[gb + 1], j2 = idxS[gb + 2];
    float w0g = wS[gb + 0], w1g = wS[gb + 1], w2g = wS[gb + 2];
    const float* f1b = f1 + (size_t)b * C1 * N;
    const float* x2b = x2 + (size_t)b * C2 * N2;
    float acc[2][4] = {{0.f, 0.f, 0.f, 0.f}, {0.f, 0.f, 0.f, 0.f}};
    for (int k0 = kBase; k0 < kBase + chunk; k0 += BK) {
        for (int t = tid; t < TO * BK; t += 256) {
            int o = t / BK, kk = t % BK;
            Ws[kk][o] = W[(size_t)(oBase + o) * Cin + k0 + kk];
        }
#pragma unroll
        for (int i = 0; i < 4; ++i) {
            int kk = kk0 + i * 4;
            int k = k0 + kk;
            float v;
            if (k < C1) {
                v = f1b[(size_t)k * N + n];
            } else {
                const float* r = x2b + (size_t)(k - C1) * N2;
                v = r[j0] * w0g + r[j1] * w1g + r[j2] * w2g;  // same expr as old concat
            }
            Xs[kk][nn] = v;
        }
        __syncthreads();
#pragma unroll
        for (int kk = 0; kk < BK; ++kk) {
            float w0 = Ws[kk][ty * 2 + 0];
            float w1 = Ws[kk][ty * 2 + 1];
            float4 xv = *reinterpret_cast<const float4*>(&Xs[kk][tx * 4]);
            acc[0][0] = fmaf(w0, xv.x, acc[0][0]);
            acc[0][1] = fmaf(w0, xv.y, acc[0][1]);
            acc[0][2] = fmaf(w0, xv.z, acc[0][2]);
            acc[0][3] = fmaf(w0, xv.w, acc[0][3]);
            acc[1][0] = fmaf(w1, xv.x, acc[1][0]);
            acc[1][1] = fmaf(w1, xv.y, acc[1][1]);
            acc[1][2] = fmaf(w1, xv.z, acc[1][2]);
            acc[1][3] = fmaf(w1, xv.w, acc[1][3]);
        }
        __syncthreads();
    }
#pragma unroll
    for (int r = 0; r < 2; ++r) {
        int o = oBase + ty * 2 + r;
        float4 st;
        if (PARTIAL) {
            st.x = acc[r][0]; st.y = acc[r][1]; st.z = acc[r][2]; st.w = acc[r][3];
            *reinterpret_cast<float4*>(&Y[((size_t)zb * Cout + o) * N + nBase + tx * 4]) = st;
        } else {
            float gg = g[o], bb = bv[o];
            st.x = fmaxf(fmaf(acc[r][0], gg, bb), 0.0f);
            st.y = fmaxf(fmaf(acc[r][1], gg, bb), 0.0f);
            st.z = fmaxf(fmaf(acc[r][2], gg, bb), 0.0f);
            st.w = fmaxf(fmaf(acc[r][3], gg, bb), 0.0f);
            *reinterpret_cast<float4*>(&Y[((size_t)b * Cout + o) * N + nBase + tx * 4]) = st;
        }
    }
}

// ------------- plain tiled GEMM for conv_b (split-K over blockIdx.z) -------------
template<bool PARTIAL>
__global__ __launch_bounds__(256) void conv_gemm_kernel(
    const float* __restrict__ X,
    const float* __restrict__ W,
    const float* __restrict__ g,
    const float* __restrict__ bv,
    float* __restrict__ Y,
    int Cin, int Cout, int N, int chunk) {
    __shared__ float Ws[BK][TO];
    __shared__ float Xs[BK][TN];
    int zb = blockIdx.z;
    int b = zb & 7;
    int split = zb >> 3;
    int kBase = split * chunk;
    int oBase = blockIdx.y * TO;
    int nBase = blockIdx.x * TN;
    int tid = threadIdx.x;
    int tx = tid & 15;
    int ty = tid >> 4;
    float acc[2][4] = {{0.f, 0.f, 0.f, 0.f}, {0.f, 0.f, 0.f, 0.f}};
    const float* Xb = X + (size_t)b * Cin * N;
    for (int k0 = kBase; k0 < kBase + chunk; k0 += BK) {
        for (int t = tid; t < TO * BK; t += 256) {
            int o = t / BK, kk = t % BK;
            Ws[kk][o] = W[(size_t)(oBase + o) * Cin + k0 + kk];
        }
        for (int t = tid; t < BK * TN; t += 256) {
            int kk = t / TN, nnn = t % TN;
            Xs[kk][nnn] = Xb[(size_t)(k0 + kk) * N + nBase + nnn];
        }
        __syncthreads();
#pragma unroll
        for (int kk = 0; kk < BK; ++kk) {
            float w0 = Ws[kk][ty * 2 + 0];
            float w1 = Ws[kk][ty * 2 + 1];
            float4 xv = *reinterpret_cast<const float4*>(&Xs[kk][tx * 4]);
            acc[0][0] = fmaf(w0, xv.x, acc[0][0]);
            acc[0][1] = fmaf(w0, xv.y, acc[0][1]);
            acc[0][2] = fmaf(w0, xv.z, acc[0][2]);
            acc[0][3] = fmaf(w0, xv.w, acc[0][3]);
            acc[1][0] = fmaf(w1, xv.x, acc[1][0]);
            acc[1][1] = fmaf(w1, xv.y, acc[1][1]);
            acc[1][2] = fmaf(w1, xv.z, acc[1][2]);
            acc[1][3] = fmaf(w1, xv.w, acc[1][3]);
        }
        __syncthreads();
    }
#pragma unroll
    for (int r = 0; r < 2; ++r) {
        int o = oBase + ty * 2 + r;
        float4 st;
        if (PARTIAL) {
            st.x = acc[r][0]; st.y = acc[r][1]; st.z = acc[r][2]; st.w = acc[r][3];
            *reinterpret_cast<float4*>(&Y[((size_t)zb * Cout + o) * N + nBase + tx * 4]) = st;
        } else {
            float gg = g[o], bb = bv[o];
            st.x = fmaxf(fmaf(acc[r][0], gg, bb), 0.0f);
            st.y = fmaxf(fmaf(acc[r][1], gg, bb), 0.0f);
            st.z = fmaxf(fmaf(acc[r][2], gg, bb), 0.0f);
            st.w = fmaxf(fmaf(acc[r][3], gg, bb), 0.0f);
            *reinterpret_cast<float4*>(&Y[((size_t)b * Cout + o) * N + nBase + tx * 4]) = st;
        }
    }
}

// ---- sum split-K partials (fixed order) + BN + ReLU ----
__global__ void reduce_bn_relu_kernel(const float* __restrict__ part,
                                      const float* __restrict__ g,
                                      const float* __restrict__ bv,
                                      float* __restrict__ Y,
                                      int Cout, int N, int total4, int nsplit, int stride4) {
    int t = blockIdx.x * blockDim.x + threadIdx.x;
    if (t >= total4) return;
    const float4* p4 = reinterpret_cast<const float4*>(part);
    float4 a = p4[t];
    for (int s = 1; s < nsplit; ++s) {
        float4 v = p4[t + (size_t)s * stride4];
        a.x += v.x; a.y += v.y; a.z += v.z; a.w += v.w;
    }
    int o = ((t * 4) / N) % Cout;
    float gg = g[o], bb = bv[o];
    float4 st;
    st.x = fmaxf(fmaf(a.x, gg, bb), 0.0f);
    st.y = fmaxf(fmaf(a.y, gg, bb), 0.0f);
    st.z = fmaxf(fmaf(a.z, gg, bb), 0.0f);
    st.w = fmaxf(fmaf(a.w, gg, bb), 0.0f);
    reinterpret_cast<float4*>(Y)[t] = st;
}

extern "C" void kernel_launch(void* const* d_in, const int* in_sizes, int n_in,
                              void* d_out, int out_size, void* d_ws, size_t ws_size,
                              hipStream_t stream) {
    const int B = 8;
    const int Ns[5]  = {8192, 2048, 512, 128, 32};
    const int CHs[5] = {32, 64, 128, 256, 512};

    const float* p[5];
    const float* f[5];
    for (int i = 0; i < 5; ++i) {
        p[i] = (const float*)d_in[2 * i];
        f[i] = (const float*)d_in[2 * i + 1];
    }

    // per-stage geometry (s=0..3, stage s: lvl = 3-s)
    int N1s[4], N2s[4], C1s[4], C2s[4];
    for (int s = 0; s < 4; ++s) {
        int lvl = 3 - s;
        N1s[s] = Ns[lvl]; N2s[s] = Ns[lvl + 1];
        C1s[s] = CHs[lvl];
        C2s[s] = (s == 0) ? CHs[4] : CHs[lvl + 1];
    }
    const int nchunks[4] = {1, 4, 8, 8};           // s0:N2=32, s1:128, s2:512, s3:2048
    int chunks[4], nbxs[4];
    for (int s = 0; s < 4; ++s) {
        chunks[s] = N2s[s] / nchunks[s];
        nbxs[s] = (N1s[s] + 255) / 256;
    }

    // ---- workspace layout (floats) ----
    float* ws = (float*)d_ws;
    int*   knn_idx = (int*)ws;                  // 262144 slots (used 261120)
    float* knn_w   = ws + 262144;               // 262144
    float* part_d  = ws + 524288;               // 2097152 (used 2018304)
    int*   part_i  = (int*)(ws + 2621440);      // 2097152
    float* bufA    = ws + 4718592;              // 2097152
    float* out0    = ws + 6815744;              // 262144
    float* out1    = ws + 7077888;              // 524288
    float* out2    = ws + 7602176;              // 1048576
    float* gpart   = ws + 8650752;              // 1572864 max
    float* outs[4] = {out0, out1, out2, (float*)d_out};

    // per-stage offsets
    int idxOff[4], pOff[4];
    {
        int a = 0, q = 0;
        for (int s = 0; s < 4; ++s) {
            idxOff[s] = a; a += B * N1s[s] * 3;
            pOff[s] = q;  q += B * N1s[s] * nchunks[s] * 3;
        }
    }

    // ---- one combined kNN launch for all stages ----
    KnnAll KP;
    int blk = 0;
    int bsArr[4];
    for (int s = 0; s < 4; ++s) {
        KP.p1[s] = p[3 - s]; KP.p2[s] = p[4 - s];
        KP.pd[s] = part_d + pOff[s]; KP.pi[s] = part_i + pOff[s];
        KP.N1[s] = N1s[s]; KP.N2[s] = N2s[s];
        KP.chunk[s] = chunks[s]; KP.nchunk[s] = nchunks[s]; KP.nbx[s] = nbxs[s];
        bsArr[s] = blk;
        blk += nbxs[s] * B * nchunks[s];
    }
    KP.bs1 = (blk, bsArr[1]); KP.bs2 = bsArr[2]; KP.bs3 = bsArr[3];
    knn_all_kernel<<<blk, 256, 0, stream>>>(KP);

    // ---- one combined merge launch ----
    MergeAll MP;
    int tt = 0;
    int tsArr[4];
    for (int s = 0; s < 4; ++s) {
        MP.pd[s] = part_d + pOff[s]; MP.pi[s] = part_i + pOff[s];
        MP.idx[s] = knn_idx + idxOff[s]; MP.w[s] = knn_w + idxOff[s];
        MP.nchunk[s] = nchunks[s]; MP.N1[s] = N1s[s];
        tsArr[s] = tt;
        tt += B * N1s[s];
    }
    MP.ts1 = tsArr[1]; MP.ts2 = tsArr[2]; MP.ts3 = tsArr[3];
    knn_merge_all_kernel<<<(tt + 255) / 256, 256, 0, stream>>>(MP);

    // split-K factors (conv_a over Cin, conv_b over Cout) — chunks stay multiples of 16
    const int nsA[4] = {6, 3, 2, 1};
    const int nsB[4] = {4, 2, 1, 1};

    for (int s = 0; s < 4; ++s) {
        int N1 = N1s[s], N2 = N2s[s];
        int C1 = C1s[s], C2 = C2s[s];
        int Cin = C1 + C2, Cout = C1;
        const float* x2 = (s == 0) ? f[4] : outs[s - 1];
        const float* wa = (const float*)d_in[10 + s * 6 + 0];
        const float* ga = (const float*)d_in[10 + s * 6 + 1];
        const float* ba = (const float*)d_in[10 + s * 6 + 2];
        const float* wb = (const float*)d_in[10 + s * 6 + 3];
        const float* gb = (const float*)d_in[10 + s * 6 + 4];
        const float* bb = (const float*)d_in[10 + s * 6 + 5];
        const int* idxS = knn_idx + idxOff[s];
        const float* wSb = knn_w + idxOff[s];

        // conv_a (fused gather-concat)
        {
            int nsplit = nsA[s];
            int chunk = Cin / nsplit;
            dim3 grid(N1 / TN, Cout / TO, B * nsplit);
            if (nsplit == 1) {
                conv_a_fused_kernel<false><<<grid, 256, 0, stream>>>(
                    f[3 - s], x2, idxS, wSb, wa, ga, ba, bufA, C1, C2, N1, N2, Cout, chunk);
            } else {
                conv_a_fused_kernel<true><<<grid, 256, 0, stream>>>(
                    f[3 - s], x2, idxS, wSb, wa, ga, ba, gpart, C1, C2, N1, N2, Cout, chunk);
                int total4 = B * Cout * N1 / 4;
                reduce_bn_relu_kernel<<<(total4 + 255) / 256, 256, 0, stream>>>(
                    gpart, ga, ba, bufA, Cout, N1, total4, nsplit, total4);
            }
        }
        // conv_b
        {
            int nsplit = nsB[s];
            int chunk = Cout / nsplit;
            dim3 grid(N1 / TN, Cout / TO, B * nsplit);
            if (nsplit == 1) {
                conv_gemm_kernel<false><<<grid, 256, 0, stream>>>(
                    bufA, wb, gb, bb, outs[s], Cout, Cout, N1, chunk);
            } else {
                conv_gemm_kernel<true><<<grid, 256, 0, stream>>>(
                    bufA, wb, gb, bb, gpart, Cout, Cout, N1, chunk);
                int total4 = B * Cout * N1 / 4;
                reduce_bn_relu_kernel<<<(total4 + 255) / 256, 256, 0, stream>>>(
                    gpart, gb, bb, outs[s], Cout, N1, total4, nsplit, total4);
            }
        }
    }
}